// Round 6
// baseline (227.120 us; speedup 1.0000x reference)
//
#include <hip/hip_runtime.h>

#define LQ 1024
#define EMB 2048
#define NH 16
#define HD 128
#define RSCALE 0.022097086912079608f   /* 1/sqrt(2048) */

typedef unsigned short u16x8 __attribute__((ext_vector_type(8)));
typedef __bf16 bf16x8 __attribute__((ext_vector_type(8)));
typedef float f32x4 __attribute__((ext_vector_type(4)));

typedef const __attribute__((address_space(1))) unsigned int* gas_t;
typedef __attribute__((address_space(3))) unsigned int* las_t;

__device__ __forceinline__ void glds16(const void* g, void* l){
  __builtin_amdgcn_global_load_lds((gas_t)g, (las_t)l, 16, 0, 0);
}
__device__ __forceinline__ unsigned short f2b(float f){
  unsigned int x = __float_as_uint(f);
  return (unsigned short)((x + 0x7fffu + ((x >> 16) & 1u)) >> 16);
}
__device__ __forceinline__ bf16x8 as_bf(u16x8 u){
  union { u16x8 u; bf16x8 b; } c; c.u = u; return c.b;
}

// ---------------- K0: prep = Wo fp32->bf16 convert  +  mask bit-pack --------
__global__ __launch_bounds__(256) void k_prep(const float* __restrict__ Wo,
                                              unsigned short* __restrict__ Wob,
                                              const int* __restrict__ M,
                                              unsigned long long* __restrict__ Mb){
  int bx = blockIdx.x, t = threadIdx.x;
  if (bx < 4096) {
    int i = (bx * 256 + t) * 4;
    float4 f = *(const float4*)&Wo[i];
    ushort4 u;
    u.x = f2b(f.x); u.y = f2b(f.y); u.z = f2b(f.z); u.w = f2b(f.w);
    *(ushort4*)&Wob[i] = u;
  } else {
    int w_idx = (bx - 4096) * 4 + (t >> 6);   // < 32768
    int lane = t & 63;
    int n = w_idx >> 14, row = (w_idx >> 4) & 1023, wc = w_idx & 15;
    int v = M[(size_t)n * (LQ * LQ) + (size_t)row * LQ + wc * 64 + lane];
    unsigned long long b = __ballot(v != 0);
    if (lane == 0) Mb[w_idx] = b;
  }
}

// ---------------- K1: RoPE (sincos fused) + projection, bf16 MFMA -----------
// C[m=(n*L+l)*H+h][o] = rope(X)[m] @ W^T ; out (n,h,l,d) bf16; Q pre-scaled
__global__ __launch_bounds__(256) void k_proj(
    const float* __restrict__ vals, const float* __restrict__ keys,
    const float* __restrict__ qrys,
    const float* __restrict__ Wv, const float* __restrict__ Wk,
    const float* __restrict__ Wq,
    unsigned short* __restrict__ vp, unsigned short* __restrict__ kp,
    unsigned short* __restrict__ qp)
{
  __shared__ unsigned short Xs[64 * 136];
  __shared__ unsigned short Ws[128 * 136];
  __shared__ float scC[4 * 128], scS[4 * 128];
  int t = threadIdx.x;
  int which = blockIdx.y;
  const float* X; const float* W; unsigned short* OUT; bool rope;
  if (which == 0)      { X = vals; W = Wv; OUT = vp; rope = false; }
  else if (which == 1) { X = keys; W = Wk; OUT = kp; rope = true;  }
  else                 { X = qrys; W = Wq; OUT = qp; rope = true;  }
  float qs = (which == 2) ? RSCALE : 1.0f;
  int m0 = blockIdx.x * 64;

  #pragma unroll
  for (int i = 0; i < 8; ++i) {
    int ci = t + 256 * i;                 // 2048 chunks of 8
    int row = ci >> 4, ch = ci & 15;
    float4 a = *(const float4*)&W[row * 128 + ch * 8];
    float4 b = *(const float4*)&W[row * 128 + ch * 8 + 4];
    u16x8 u;
    u[0]=f2b(a.x); u[1]=f2b(a.y); u[2]=f2b(a.z); u[3]=f2b(a.w);
    u[4]=f2b(b.x); u[5]=f2b(b.y); u[6]=f2b(b.z); u[7]=f2b(b.w);
    *(u16x8*)&Ws[row * 136 + ch * 8] = u;
  }
  if (rope) {
    int l0 = (blockIdx.x * 4) & 1023;
    #pragma unroll
    for (int i = 0; i < 2; ++i) {
      int idx = t + 256 * i;              // < 512
      int li = idx >> 7, d = idx & 127, j = d & 63;
      float inv = 1.0f / powf(10000.0f, (float)(2 * j) * 0.0078125f);
      float ang = (float)(l0 + li) * inv;
      scC[idx] = cosf(ang);
      scS[idx] = sinf(ang);
    }
  }
  __syncthreads();
  #pragma unroll
  for (int i = 0; i < 8; ++i) {
    int fi = t + 256 * i;                 // 2048 float4 groups
    int row = fi >> 5, dq = (fi & 31) * 4;
    int gr = m0 + row;
    float4 x = *(const float4*)&X[(size_t)gr * HD + dq];
    ushort4 u;
    if (rope) {
      int li = row >> 4;
      float4 xm = *(const float4*)&X[(size_t)gr * HD + (124 - dq)];
      float4 c  = *(const float4*)&scC[li * 128 + dq];
      float4 s  = *(const float4*)&scS[li * 128 + dq];
      u.x = f2b(x.x * c.x + xm.w * s.x);
      u.y = f2b(x.y * c.y + xm.z * s.y);
      u.z = f2b(x.z * c.z + xm.y * s.z);
      u.w = f2b(x.w * c.w + xm.x * s.w);
    } else {
      u.x = f2b(x.x); u.y = f2b(x.y); u.z = f2b(x.z); u.w = f2b(x.w);
    }
    *(ushort4*)&Xs[row * 136 + dq] = u;
  }
  __syncthreads();

  int w = t >> 6, lane = t & 63, quad = lane >> 4, n16 = lane & 15;
  f32x4 of[4][2];
  #pragma unroll
  for (int a = 0; a < 4; ++a)
    { of[a][0] = (f32x4){0.f,0.f,0.f,0.f}; of[a][1] = (f32x4){0.f,0.f,0.f,0.f}; }

  #pragma unroll
  for (int kd = 0; kd < 4; ++kd) {
    bf16x8 bfr[2];
    #pragma unroll
    for (int b2 = 0; b2 < 2; ++b2)
      bfr[b2] = as_bf(*(const u16x8*)&Ws[(w * 32 + b2 * 16 + n16) * 136 + kd * 32 + quad * 8]);
    #pragma unroll
    for (int a = 0; a < 4; ++a) {
      bf16x8 af = as_bf(*(const u16x8*)&Xs[(a * 16 + n16) * 136 + kd * 32 + quad * 8]);
      of[a][0] = __builtin_amdgcn_mfma_f32_16x16x32_bf16(af, bfr[0], of[a][0], 0, 0, 0);
      of[a][1] = __builtin_amdgcn_mfma_f32_16x16x32_bf16(af, bfr[1], of[a][1], 0, 0, 0);
    }
  }

  #pragma unroll
  for (int a = 0; a < 4; ++a) {
    #pragma unroll
    for (int b2 = 0; b2 < 2; ++b2) {
      #pragma unroll
      for (int r = 0; r < 4; ++r) {
        int m = m0 + a * 16 + quad * 4 + r;
        int n = m >> 14, l = (m >> 4) & 1023, h = m & 15;
        int o = w * 32 + b2 * 16 + n16;
        OUT[(((size_t)(n * NH + h)) * LQ + l) * HD + o] = f2b(of[a][b2][r] * qs);
      }
    }
  }
}

// ---------------- K1b: transpose V (n,h,l,d) -> (n,h,d,l) ----------------
__global__ __launch_bounds__(256) void k_vtrans(const unsigned short* __restrict__ vp,
                                                unsigned short* __restrict__ vt){
  __shared__ unsigned short Ls[64 * 136];
  int t = threadIdx.x;
  int l0 = blockIdx.x * 64;
  size_t base = (size_t)blockIdx.y * LQ * HD;     // nh
  #pragma unroll
  for (int i = 0; i < 4; ++i) {
    int ci = t + 256 * i;                 // 1024 chunks
    int row = ci >> 4, ch = ci & 15;
    *(u16x8*)&Ls[row * 136 + ch * 8] =
        *(const u16x8*)&vp[base + (size_t)(l0 + row) * HD + ch * 8];
  }
  __syncthreads();
  #pragma unroll
  for (int i = 0; i < 4; ++i) {
    int idx = t + 256 * i;
    int d = idx & 127, lc = idx >> 7;     // conflict-free gather (d across lanes)
    u16x8 pk;
    #pragma unroll
    for (int j = 0; j < 8; ++j) pk[j] = Ls[(lc * 8 + j) * 136 + d];
    *(u16x8*)&vt[base + (size_t)d * LQ + l0 + lc * 8] = pk;
  }
}

// ---------------- K2: MFMA flash attention, dbuf glds, no-max softmax -------
__global__ __launch_bounds__(256) void k_attn(
    const unsigned short* __restrict__ qp, const unsigned short* __restrict__ kp,
    const unsigned short* __restrict__ vt, const unsigned long long* __restrict__ Mb,
    unsigned short* __restrict__ ao)
{
  __shared__ unsigned short Ks[2][64 * 128];   // slot=chunk^(row&7)
  __shared__ unsigned short Vt[2][128 * 64];
  __shared__ unsigned short Ss[4 * 16 * 76];   // stride 76 u16 (2-way banks)
  int t = threadIdx.x, w = t >> 6, lane = t & 63, quad = lane >> 4, n16 = lane & 15;
  int bh = blockIdx.y, nIdx = bh >> 4, h = bh & 15;
  int q0 = blockIdx.x * 64;
  size_t base = (size_t)bh * LQ * HD;
  const unsigned short* Q = qp + base;
  const unsigned short* K = kp + base;
  const unsigned short* V = vt + base;            // (d, l)

  bf16x8 qf[4];
  #pragma unroll
  for (int kd = 0; kd < 4; ++kd)
    qf[kd] = as_bf(*(const u16x8*)&Q[(size_t)(q0 + w * 16 + n16) * HD + kd * 32 + quad * 8]);

  const unsigned long long* MbRow =
      Mb + ((size_t)nIdx * LQ + q0 + w * 16 + quad * 4) * 16;

  f32x4 of[8];
  #pragma unroll
  for (int c = 0; c < 8; ++c) of[c] = (f32x4){0.f, 0.f, 0.f, 0.f};
  float lp[4] = {0.f, 0.f, 0.f, 0.f};
  unsigned short* Ssw = Ss + w * 1216;
  int ub = (t & 192);                       // wave-uniform thread base

  // mask prefetch (iter 0) + stage tile 0 into buf 0
  unsigned long long mw[4];
  #pragma unroll
  for (int r = 0; r < 4; ++r) mw[r] = MbRow[r * 16];
  #pragma unroll
  for (int i = 0; i < 4; ++i) {
    int ci = t + 256 * i;
    int krow = ci >> 4, kch = (ci & 15) ^ (krow & 7);
    glds16(&K[(size_t)krow * HD + kch * 8], &Ks[0][(ub + 256 * i) * 8]);
    int vrow = ci >> 3, vch = (ci & 7) ^ (vrow & 7);
    glds16(&V[(size_t)vrow * LQ + vch * 8], &Vt[0][(ub + 256 * i) * 8]);
  }

  for (int kt = 0; kt < 16; ++kt) {
    int cur = kt & 1;
    __syncthreads();                        // drains buf[cur] glds (overlapped)
    unsigned long long mwn[4];
    if (kt < 15) {
      int k1 = (kt + 1) * 64;
      #pragma unroll
      for (int i = 0; i < 4; ++i) {
        int ci = t + 256 * i;
        int krow = ci >> 4, kch = (ci & 15) ^ (krow & 7);
        glds16(&K[(size_t)(k1 + krow) * HD + kch * 8], &Ks[1 - cur][(ub + 256 * i) * 8]);
        int vrow = ci >> 3, vch = (ci & 7) ^ (vrow & 7);
        glds16(&V[(size_t)vrow * LQ + k1 + vch * 8], &Vt[1 - cur][(ub + 256 * i) * 8]);
      }
      #pragma unroll
      for (int r = 0; r < 4; ++r) mwn[r] = MbRow[r * 16 + kt + 1];
    }

    // ---- S = Q K^T ----
    f32x4 sf[4];
    #pragma unroll
    for (int c = 0; c < 4; ++c) sf[c] = (f32x4){0.f, 0.f, 0.f, 0.f};
    #pragma unroll
    for (int kd = 0; kd < 4; ++kd) {
      #pragma unroll
      for (int c = 0; c < 4; ++c) {
        int slot = (kd * 4 + quad) ^ (n16 & 7);
        bf16x8 kv = as_bf(*(const u16x8*)&Ks[cur][(c * 16 + n16) * 128 + slot * 8]);
        sf[c] = __builtin_amdgcn_mfma_f32_16x16x32_bf16(qf[kd], kv, sf[c], 0, 0, 0);
      }
    }
    // ---- no-max softmax: p = bit ? exp(s) : 0  (Q pre-scaled) ----
    #pragma unroll
    for (int r = 0; r < 4; ++r) {
      #pragma unroll
      for (int c = 0; c < 4; ++c) {
        int bit = (int)((mw[r] >> (c * 16 + n16)) & 1ull);
        float p = bit ? __expf(sf[c][r]) : 0.f;
        lp[r] += p;
        Ssw[(quad * 4 + r) * 76 + c * 16 + n16] = f2b(p);
      }
    }
    // ---- O += P V ----
    #pragma unroll
    for (int ks = 0; ks < 2; ++ks) {
      bf16x8 pa = as_bf(*(const u16x8*)&Ssw[n16 * 76 + ks * 32 + quad * 8]);
      #pragma unroll
      for (int c2 = 0; c2 < 8; ++c2) {
        int slot = (ks * 4 + quad) ^ (n16 & 7);
        bf16x8 vv = as_bf(*(const u16x8*)&Vt[cur][(c2 * 16 + n16) * 64 + slot * 8]);
        of[c2] = __builtin_amdgcn_mfma_f32_16x16x32_bf16(pa, vv, of[c2], 0, 0, 0);
      }
    }
    #pragma unroll
    for (int r = 0; r < 4; ++r) mw[r] = mwn[r];
  }

  #pragma unroll
  for (int r = 0; r < 4; ++r) {
    float s = lp[r];
    #pragma unroll
    for (int off = 1; off < 16; off <<= 1) s += __shfl_xor(s, off, 16);
    lp[r] = 1.0f / fmaxf(s, 1e-30f);
  }
  #pragma unroll
  for (int c2 = 0; c2 < 8; ++c2) {
    #pragma unroll
    for (int r = 0; r < 4; ++r) {
      ao[((size_t)(nIdx * LQ + q0 + w * 16 + quad * 4 + r)) * EMB + h * HD + c2 * 16 + n16] =
          f2b(of[c2][r] * lp[r]);
    }
  }
}

// ---------------- K3: output projection, 128x128, BK=64, dbuf glds ----------
__global__ __launch_bounds__(256) void k_outproj(
    const unsigned short* __restrict__ ao, const unsigned short* __restrict__ Wob,
    const float* __restrict__ bo, float* __restrict__ out)
{
  __shared__ unsigned short As[2][128 * 64];   // slot=chunk^(row&7)
  __shared__ unsigned short Bs[2][128 * 64];
  int t = threadIdx.x;
  int w = t >> 6, lane = t & 63, quad = lane >> 4, n16 = lane & 15;
  int wm = w >> 1, wo = w & 1;
  int m0 = blockIdx.x * 128, o0 = blockIdx.y * 128;
  int ub = (t & 192);

  f32x4 of[4][4];
  #pragma unroll
  for (int a = 0; a < 4; ++a)
    #pragma unroll
    for (int b = 0; b < 4; ++b) of[a][b] = (f32x4){0.f, 0.f, 0.f, 0.f};

  #pragma unroll
  for (int i = 0; i < 4; ++i) {
    int ci = t + 256 * i;
    int row = ci >> 3, ch = (ci & 7) ^ (row & 7);
    glds16(&ao [(size_t)(m0 + row) * EMB + ch * 8], &As[0][(ub + 256 * i) * 8]);
    glds16(&Wob[(size_t)(o0 + row) * EMB + ch * 8], &Bs[0][(ub + 256 * i) * 8]);
  }

  for (int kt = 0; kt < 32; ++kt) {
    int cur = kt & 1;
    __syncthreads();
    if (kt < 31) {
      int k1 = (kt + 1) * 64;
      #pragma unroll
      for (int i = 0; i < 4; ++i) {
        int ci = t + 256 * i;
        int row = ci >> 3, ch = (ci & 7) ^ (row & 7);
        glds16(&ao [(size_t)(m0 + row) * EMB + k1 + ch * 8], &As[1 - cur][(ub + 256 * i) * 8]);
        glds16(&Wob[(size_t)(o0 + row) * EMB + k1 + ch * 8], &Bs[1 - cur][(ub + 256 * i) * 8]);
      }
    }
    #pragma unroll
    for (int kd = 0; kd < 2; ++kd) {
      bf16x8 af[4], bf[4];
      #pragma unroll
      for (int a = 0; a < 4; ++a) {
        int slot = (kd * 4 + quad) ^ (n16 & 7);
        af[a] = as_bf(*(const u16x8*)&As[cur][(wm * 64 + a * 16 + n16) * 64 + slot * 8]);
      }
      #pragma unroll
      for (int b = 0; b < 4; ++b) {
        int slot = (kd * 4 + quad) ^ (n16 & 7);
        bf[b] = as_bf(*(const u16x8*)&Bs[cur][(wo * 64 + b * 16 + n16) * 64 + slot * 8]);
      }
      #pragma unroll
      for (int a = 0; a < 4; ++a)
        #pragma unroll
        for (int b = 0; b < 4; ++b)
          of[a][b] = __builtin_amdgcn_mfma_f32_16x16x32_bf16(af[a], bf[b], of[a][b], 0, 0, 0);
    }
  }

  float bb[4];
  #pragma unroll
  for (int b = 0; b < 4; ++b) bb[b] = bo[o0 + wo * 64 + b * 16 + n16];
  #pragma unroll
  for (int a = 0; a < 4; ++a) {
    #pragma unroll
    for (int b = 0; b < 4; ++b) {
      #pragma unroll
      for (int r = 0; r < 4; ++r) {
        out[(size_t)(m0 + wm * 64 + a * 16 + quad * 4 + r) * EMB
            + o0 + wo * 64 + b * 16 + n16] = of[a][b][r] + bb[b];
      }
    }
  }
}

extern "C" void kernel_launch(void* const* d_in, const int* in_sizes, int n_in,
                              void* d_out, int out_size, void* d_ws, size_t ws_size,
                              hipStream_t stream) {
  (void)in_sizes; (void)n_in; (void)out_size; (void)ws_size;
  const float* vals = (const float*)d_in[0];
  const float* keys = (const float*)d_in[1];
  const float* qrys = (const float*)d_in[2];
  const int*   mask = (const int*)d_in[3];
  const float* Wv   = (const float*)d_in[4];
  const float* Wk   = (const float*)d_in[5];
  const float* Wq   = (const float*)d_in[6];
  const float* Wo   = (const float*)d_in[7];
  const float* bo   = (const float*)d_in[8];
  float* out = (float*)d_out;

  unsigned short* U  = (unsigned short*)d_ws;
  unsigned short* qp = U;                              // (n,h,l,d) bf16
  unsigned short* kp = U + 4194304;
  unsigned short* vp = U + 8388608;
  unsigned short* vt = U + 12582912;                   // (n,h,d,l) bf16
  unsigned short* ao = U + 16777216;                   // (n,l,e) bf16
  unsigned short* Wob= U + 20971520;                   // Wo bf16
  unsigned long long* Mb = (unsigned long long*)(U + 25165824);  // 32768 u64

  k_prep    <<<dim3(12288),  dim3(256), 0, stream>>>(Wo, Wob, mask, Mb);
  k_proj    <<<dim3(512, 3), dim3(256), 0, stream>>>(vals, keys, qrys, Wv, Wk, Wq,
                                                     vp, kp, qp);
  k_vtrans  <<<dim3(16, 32), dim3(256), 0, stream>>>(vp, vt);
  k_attn    <<<dim3(16, 32), dim3(256), 0, stream>>>(qp, kp, vt, Mb, ao);
  k_outproj <<<dim3(16, 16), dim3(256), 0, stream>>>(ao, Wob, bo, out);
}

// Round 8
// 214.279 us; speedup vs baseline: 1.0599x; 1.0599x over previous
//
#include <hip/hip_runtime.h>

#define LQ 1024
#define EMB 2048
#define NH 16
#define HD 128
#define RSCALE 0.022097086912079608f   /* 1/sqrt(2048) */

typedef unsigned short u16x8 __attribute__((ext_vector_type(8)));
typedef __bf16 bf16x8 __attribute__((ext_vector_type(8)));
typedef float f32x4 __attribute__((ext_vector_type(4)));
typedef short s16x4 __attribute__((ext_vector_type(4)));

typedef const __attribute__((address_space(1))) unsigned int* gas_t;
typedef __attribute__((address_space(3))) unsigned int* las_t;

__device__ __forceinline__ void glds16(const void* g, void* l){
  __builtin_amdgcn_global_load_lds((gas_t)g, (las_t)l, 16, 0, 0);
}
__device__ __forceinline__ unsigned short f2b(float f){
  unsigned int x = __float_as_uint(f);
  return (unsigned short)((x + 0x7fffu + ((x >> 16) & 1u)) >> 16);
}
__device__ __forceinline__ bf16x8 as_bf(u16x8 u){
  union { u16x8 u; bf16x8 b; } c; c.u = u; return c.b;
}
// K=16 bf16 MFMA (v_mfma_f32_16x16x16_bf16, gfx90a-lineage builtin, valid gfx950)
__device__ __forceinline__ f32x4 mfma16(s16x4 a, s16x4 b, f32x4 c){
  return __builtin_amdgcn_mfma_f32_16x16x16bf16_1k(a, b, c, 0, 0, 0);
}

// ---------------- K0: prep = Wo fp32->bf16 convert  +  mask bit-pack --------
__global__ __launch_bounds__(256) void k_prep(const float* __restrict__ Wo,
                                              unsigned short* __restrict__ Wob,
                                              const int* __restrict__ M,
                                              unsigned long long* __restrict__ Mb){
  int bx = blockIdx.x, t = threadIdx.x;
  if (bx < 4096) {
    int i = (bx * 256 + t) * 4;
    float4 f = *(const float4*)&Wo[i];
    ushort4 u;
    u.x = f2b(f.x); u.y = f2b(f.y); u.z = f2b(f.z); u.w = f2b(f.w);
    *(ushort4*)&Wob[i] = u;
  } else {
    int w_idx = (bx - 4096) * 4 + (t >> 6);   // < 32768
    int lane = t & 63;
    int n = w_idx >> 14, row = (w_idx >> 4) & 1023, wc = w_idx & 15;
    int v = M[(size_t)n * (LQ * LQ) + (size_t)row * LQ + wc * 64 + lane];
    unsigned long long b = __ballot(v != 0);
    if (lane == 0) Mb[w_idx] = b;
  }
}

// ---------------- K1: RoPE (sincos fused) + projection, bf16 MFMA -----------
__global__ __launch_bounds__(256) void k_proj(
    const float* __restrict__ vals, const float* __restrict__ keys,
    const float* __restrict__ qrys,
    const float* __restrict__ Wv, const float* __restrict__ Wk,
    const float* __restrict__ Wq,
    unsigned short* __restrict__ vp, unsigned short* __restrict__ kp,
    unsigned short* __restrict__ qp)
{
  __shared__ unsigned short Xs[64 * 136];
  __shared__ unsigned short Ws[128 * 136];
  __shared__ float scC[4 * 128], scS[4 * 128];
  int t = threadIdx.x;
  int which = blockIdx.y;
  const float* X; const float* W; unsigned short* OUT; bool rope;
  if (which == 0)      { X = vals; W = Wv; OUT = vp; rope = false; }
  else if (which == 1) { X = keys; W = Wk; OUT = kp; rope = true;  }
  else                 { X = qrys; W = Wq; OUT = qp; rope = true;  }
  float qs = (which == 2) ? RSCALE : 1.0f;
  int m0 = blockIdx.x * 64;

  #pragma unroll
  for (int i = 0; i < 8; ++i) {
    int ci = t + 256 * i;
    int row = ci >> 4, ch = ci & 15;
    float4 a = *(const float4*)&W[row * 128 + ch * 8];
    float4 b = *(const float4*)&W[row * 128 + ch * 8 + 4];
    u16x8 u;
    u[0]=f2b(a.x); u[1]=f2b(a.y); u[2]=f2b(a.z); u[3]=f2b(a.w);
    u[4]=f2b(b.x); u[5]=f2b(b.y); u[6]=f2b(b.z); u[7]=f2b(b.w);
    *(u16x8*)&Ws[row * 136 + ch * 8] = u;
  }
  if (rope) {
    int l0 = (blockIdx.x * 4) & 1023;
    #pragma unroll
    for (int i = 0; i < 2; ++i) {
      int idx = t + 256 * i;
      int li = idx >> 7, d = idx & 127, j = d & 63;
      float inv = 1.0f / powf(10000.0f, (float)(2 * j) * 0.0078125f);
      float ang = (float)(l0 + li) * inv;
      scC[idx] = cosf(ang);
      scS[idx] = sinf(ang);
    }
  }
  __syncthreads();
  #pragma unroll
  for (int i = 0; i < 8; ++i) {
    int fi = t + 256 * i;
    int row = fi >> 5, dq = (fi & 31) * 4;
    int gr = m0 + row;
    float4 x = *(const float4*)&X[(size_t)gr * HD + dq];
    ushort4 u;
    if (rope) {
      int li = row >> 4;
      float4 xm = *(const float4*)&X[(size_t)gr * HD + (124 - dq)];
      float4 c  = *(const float4*)&scC[li * 128 + dq];
      float4 s  = *(const float4*)&scS[li * 128 + dq];
      u.x = f2b(x.x * c.x + xm.w * s.x);
      u.y = f2b(x.y * c.y + xm.z * s.y);
      u.z = f2b(x.z * c.z + xm.y * s.z);
      u.w = f2b(x.w * c.w + xm.x * s.w);
    } else {
      u.x = f2b(x.x); u.y = f2b(x.y); u.z = f2b(x.z); u.w = f2b(x.w);
    }
    *(ushort4*)&Xs[row * 136 + dq] = u;
  }
  __syncthreads();

  int w = t >> 6, lane = t & 63, quad = lane >> 4, n16 = lane & 15;
  f32x4 of[4][2];
  #pragma unroll
  for (int a = 0; a < 4; ++a)
    { of[a][0] = (f32x4){0.f,0.f,0.f,0.f}; of[a][1] = (f32x4){0.f,0.f,0.f,0.f}; }

  #pragma unroll
  for (int kd = 0; kd < 4; ++kd) {
    bf16x8 bfr[2];
    #pragma unroll
    for (int b2 = 0; b2 < 2; ++b2)
      bfr[b2] = as_bf(*(const u16x8*)&Ws[(w * 32 + b2 * 16 + n16) * 136 + kd * 32 + quad * 8]);
    #pragma unroll
    for (int a = 0; a < 4; ++a) {
      bf16x8 af = as_bf(*(const u16x8*)&Xs[(a * 16 + n16) * 136 + kd * 32 + quad * 8]);
      of[a][0] = __builtin_amdgcn_mfma_f32_16x16x32_bf16(af, bfr[0], of[a][0], 0, 0, 0);
      of[a][1] = __builtin_amdgcn_mfma_f32_16x16x32_bf16(af, bfr[1], of[a][1], 0, 0, 0);
    }
  }

  #pragma unroll
  for (int a = 0; a < 4; ++a) {
    #pragma unroll
    for (int b2 = 0; b2 < 2; ++b2) {
      #pragma unroll
      for (int r = 0; r < 4; ++r) {
        int m = m0 + a * 16 + quad * 4 + r;
        int n = m >> 14, l = (m >> 4) & 1023, h = m & 15;
        int o = w * 32 + b2 * 16 + n16;
        OUT[(((size_t)(n * NH + h)) * LQ + l) * HD + o] = f2b(of[a][b2][r] * qs);
      }
    }
  }
}

// ---------------- K1b: transpose V (n,h,l,d) -> (n,h,d,l) ----------------
__global__ __launch_bounds__(256) void k_vtrans(const unsigned short* __restrict__ vp,
                                                unsigned short* __restrict__ vt){
  __shared__ unsigned short Ls[64 * 136];
  int t = threadIdx.x;
  int l0 = blockIdx.x * 64;
  size_t base = (size_t)blockIdx.y * LQ * HD;
  #pragma unroll
  for (int i = 0; i < 4; ++i) {
    int ci = t + 256 * i;
    int row = ci >> 4, ch = ci & 15;
    *(u16x8*)&Ls[row * 136 + ch * 8] =
        *(const u16x8*)&vp[base + (size_t)(l0 + row) * HD + ch * 8];
  }
  __syncthreads();
  #pragma unroll
  for (int i = 0; i < 4; ++i) {
    int idx = t + 256 * i;
    int d = idx & 127, lc = idx >> 7;
    u16x8 pk;
    #pragma unroll
    for (int j = 0; j < 8; ++j) pk[j] = Ls[(lc * 8 + j) * 136 + d];
    *(u16x8*)&vt[base + (size_t)d * LQ + l0 + lc * 8] = pk;
  }
}

// ---------------- K2: MFMA flash attention, S^T trick, no P round-trip ------
// S^T = K·Q^T puts P in A-layout of the K=16 MFMA: PV feeds from registers.
__global__ __launch_bounds__(256) void k_attn(
    const unsigned short* __restrict__ qp, const unsigned short* __restrict__ kp,
    const unsigned short* __restrict__ vt, const unsigned long long* __restrict__ Mb,
    unsigned short* __restrict__ ao)
{
  __shared__ unsigned short Ks[64 * 128];   // rows=kpos, 16 chunks, slot=ch^(row&7)
  __shared__ unsigned short Vt[128 * 64];   // rows=d, 8 chunks, slot=ch^(row&7)
  __shared__ float ls[4][16];
  int t = threadIdx.x, w = t >> 6, lane = t & 63, quad = lane >> 4, n16 = lane & 15;
  int bh = blockIdx.y, nIdx = bh >> 4, h = bh & 15;
  int q0 = blockIdx.x * 64;
  size_t base = (size_t)bh * LQ * HD;
  const unsigned short* Q = qp + base;
  const unsigned short* K = kp + base;
  const unsigned short* V = vt + base;            // (d, l)

  // Q fragments (B-operand of S^T MFMA): B[n=q=n16][k=d=kd*32+quad*8+j]
  bf16x8 qf[4];
  #pragma unroll
  for (int kd = 0; kd < 4; ++kd)
    qf[kd] = as_bf(*(const u16x8*)&Q[(size_t)(q0 + w * 16 + n16) * HD + kd * 32 + quad * 8]);

  // one mask word per lane per iter: q = n16
  const unsigned long long* MbRow =
      Mb + ((size_t)nIdx * LQ + q0 + w * 16 + n16) * 16;

  f32x4 of[8];
  #pragma unroll
  for (int c = 0; c < 8; ++c) of[c] = (f32x4){0.f, 0.f, 0.f, 0.f};
  float lp = 0.f;                          // per-lane partial of l[q=n16]
  int ub = (t & 192);

  for (int kt = 0; kt < 16; ++kt) {
    int k0 = kt * 64;
    __syncthreads();
    #pragma unroll
    for (int i = 0; i < 4; ++i) {
      int ci = t + 256 * i;
      int krow = ci >> 4, kch = (ci & 15) ^ (krow & 7);
      glds16(&K[(size_t)(k0 + krow) * HD + kch * 8], &Ks[(ub + 256 * i) * 8]);
      int vrow = ci >> 3, vch = (ci & 7) ^ (vrow & 7);
      glds16(&V[(size_t)vrow * LQ + k0 + vch * 8], &Vt[(ub + 256 * i) * 8]);
    }
    unsigned long long mq = MbRow[kt];
    __syncthreads();

    // ---- S^T = K Q^T : rows kpos, cols q ----
    f32x4 sf[4];
    #pragma unroll
    for (int c = 0; c < 4; ++c) sf[c] = (f32x4){0.f, 0.f, 0.f, 0.f};
    #pragma unroll
    for (int kd = 0; kd < 4; ++kd) {
      #pragma unroll
      for (int c = 0; c < 4; ++c) {
        int slot = (kd * 4 + quad) ^ (n16 & 7);
        bf16x8 kv = as_bf(*(const u16x8*)&Ks[(c * 16 + n16) * 128 + slot * 8]);
        sf[c] = __builtin_amdgcn_mfma_f32_16x16x32_bf16(kv, qf[kd], sf[c], 0, 0, 0);
      }
    }
    // ---- softmax numerators + PV (P stays in registers) ----
    #pragma unroll
    for (int c = 0; c < 4; ++c) {
      s16x4 pa;
      #pragma unroll
      for (int r = 0; r < 4; ++r) {
        int bit = (int)((mq >> (c * 16 + quad * 4 + r)) & 1ull);
        float p = bit ? __expf(sf[c][r]) : 0.f;
        lp += p;
        pa[r] = (short)f2b(p);
      }
      int cc = 2 * c + (quad >> 1);
      #pragma unroll
      for (int c2 = 0; c2 < 8; ++c2) {
        int row = c2 * 16 + n16;
        int slot = cc ^ (n16 & 7);
        s16x4 vv = *(const s16x4*)&Vt[row * 64 + slot * 8 + (quad & 1) * 4];
        of[c2] = mfma16(pa, vv, of[c2]);
      }
    }
  }

  // l: reduce over quads, redistribute q: n16 -> quad*4+r via LDS
  {
    float s = lp;
    s += __shfl_xor(s, 16);
    s += __shfl_xor(s, 32);
    ls[w][n16] = s;
  }
  __syncthreads();
  float linv[4];
  #pragma unroll
  for (int r = 0; r < 4; ++r) linv[r] = 1.0f / fmaxf(ls[w][quad * 4 + r], 1e-30f);

  #pragma unroll
  for (int c2 = 0; c2 < 8; ++c2) {
    #pragma unroll
    for (int r = 0; r < 4; ++r) {
      ao[((size_t)(nIdx * LQ + q0 + w * 16 + quad * 4 + r)) * EMB + h * HD + c2 * 16 + n16] =
          f2b(of[c2][r] * linv[r]);
    }
  }
}

// ---------------- K3: output projection, 128x64 tiles, BK=64, dbuf glds -----
__global__ __launch_bounds__(256) void k_outproj(
    const unsigned short* __restrict__ ao, const unsigned short* __restrict__ Wob,
    const float* __restrict__ bo, float* __restrict__ out)
{
  __shared__ unsigned short As[2][128 * 64];   // slot=chunk^(row&7)
  __shared__ unsigned short Bs[2][64 * 64];
  int t = threadIdx.x;
  int w = t >> 6, lane = t & 63, quad = lane >> 4, n16 = lane & 15;
  int wm = w >> 1, wo = w & 1;
  int m0 = blockIdx.x * 128, o0 = blockIdx.y * 64;
  int ub = (t & 192);

  f32x4 of[4][2];
  #pragma unroll
  for (int a = 0; a < 4; ++a)
    { of[a][0] = (f32x4){0.f,0.f,0.f,0.f}; of[a][1] = (f32x4){0.f,0.f,0.f,0.f}; }

  #pragma unroll
  for (int i = 0; i < 4; ++i) {
    int ci = t + 256 * i;
    int row = ci >> 3, ch = (ci & 7) ^ (row & 7);
    glds16(&ao[(size_t)(m0 + row) * EMB + ch * 8], &As[0][(ub + 256 * i) * 8]);
  }
  #pragma unroll
  for (int i = 0; i < 2; ++i) {
    int ci = t + 256 * i;
    int row = ci >> 3, ch = (ci & 7) ^ (row & 7);
    glds16(&Wob[(size_t)(o0 + row) * EMB + ch * 8], &Bs[0][(ub + 256 * i) * 8]);
  }

  for (int kt = 0; kt < 32; ++kt) {
    int cur = kt & 1;
    __syncthreads();
    if (kt < 31) {
      int k1 = (kt + 1) * 64;
      #pragma unroll
      for (int i = 0; i < 4; ++i) {
        int ci = t + 256 * i;
        int row = ci >> 3, ch = (ci & 7) ^ (row & 7);
        glds16(&ao[(size_t)(m0 + row) * EMB + k1 + ch * 8], &As[1 - cur][(ub + 256 * i) * 8]);
      }
      #pragma unroll
      for (int i = 0; i < 2; ++i) {
        int ci = t + 256 * i;
        int row = ci >> 3, ch = (ci & 7) ^ (row & 7);
        glds16(&Wob[(size_t)(o0 + row) * EMB + k1 + ch * 8], &Bs[1 - cur][(ub + 256 * i) * 8]);
      }
    }
    #pragma unroll
    for (int kd = 0; kd < 2; ++kd) {
      int slot0 = (kd * 4 + quad);
      bf16x8 af[4], bf[2];
      #pragma unroll
      for (int a = 0; a < 4; ++a)
        af[a] = as_bf(*(const u16x8*)&As[cur][(wm * 64 + a * 16 + n16) * 64 + (slot0 ^ (n16 & 7)) * 8]);
      #pragma unroll
      for (int b = 0; b < 2; ++b)
        bf[b] = as_bf(*(const u16x8*)&Bs[cur][(wo * 32 + b * 16 + n16) * 64 + (slot0 ^ (n16 & 7)) * 8]);
      #pragma unroll
      for (int a = 0; a < 4; ++a)
        #pragma unroll
        for (int b = 0; b < 2; ++b)
          of[a][b] = __builtin_amdgcn_mfma_f32_16x16x32_bf16(af[a], bf[b], of[a][b], 0, 0, 0);
    }
  }

  float bb[2] = { bo[o0 + wo * 32 + n16], bo[o0 + wo * 32 + 16 + n16] };
  #pragma unroll
  for (int a = 0; a < 4; ++a) {
    #pragma unroll
    for (int b = 0; b < 2; ++b) {
      #pragma unroll
      for (int r = 0; r < 4; ++r) {
        out[(size_t)(m0 + wm * 64 + a * 16 + quad * 4 + r) * EMB
            + o0 + wo * 32 + b * 16 + n16] = of[a][b][r] + bb[b];
      }
    }
  }
}

extern "C" void kernel_launch(void* const* d_in, const int* in_sizes, int n_in,
                              void* d_out, int out_size, void* d_ws, size_t ws_size,
                              hipStream_t stream) {
  (void)in_sizes; (void)n_in; (void)out_size; (void)ws_size;
  const float* vals = (const float*)d_in[0];
  const float* keys = (const float*)d_in[1];
  const float* qrys = (const float*)d_in[2];
  const int*   mask = (const int*)d_in[3];
  const float* Wv   = (const float*)d_in[4];
  const float* Wk   = (const float*)d_in[5];
  const float* Wq   = (const float*)d_in[6];
  const float* Wo   = (const float*)d_in[7];
  const float* bo   = (const float*)d_in[8];
  float* out = (float*)d_out;

  unsigned short* U  = (unsigned short*)d_ws;
  unsigned short* qp = U;                              // (n,h,l,d) bf16
  unsigned short* kp = U + 4194304;
  unsigned short* vp = U + 8388608;
  unsigned short* vt = U + 12582912;                   // (n,h,d,l) bf16
  unsigned short* ao = U + 16777216;                   // (n,l,e) bf16
  unsigned short* Wob= U + 20971520;                   // Wo bf16
  unsigned long long* Mb = (unsigned long long*)(U + 25165824);  // 32768 u64

  k_prep    <<<dim3(12288),  dim3(256), 0, stream>>>(Wo, Wob, mask, Mb);
  k_proj    <<<dim3(512, 3), dim3(256), 0, stream>>>(vals, keys, qrys, Wv, Wk, Wq,
                                                     vp, kp, qp);
  k_vtrans  <<<dim3(16, 32), dim3(256), 0, stream>>>(vp, vt);
  k_attn    <<<dim3(16, 32), dim3(256), 0, stream>>>(qp, kp, vt, Mb, ao);
  k_outproj <<<dim3(16, 32), dim3(256), 0, stream>>>(ao, Wob, bo, out);
}